// Round 1
// baseline (368.985 us; speedup 1.0000x reference)
//
#include <hip/hip_runtime.h>

// Problem constants (from reference)
#define BB   16
#define CC   16
#define HH   256
#define WW   256
#define HID  128
#define OUTC 13
#define PC   48   // 3*C perception channels

// Tile config
#define TW 32
#define TH 8

__global__ __launch_bounds__(256) void gca_kernel(
    const float* __restrict__ x,
    const float* __restrict__ w1,
    const float* __restrict__ b1,
    const float* __restrict__ w2,
    float* __restrict__ out)
{
    // LDS tile with 1-halo, per channel: 16 * 10 * 34 * 4B = 21760 B
    __shared__ float tile[CC][TH + 2][TW + 2];

    const int blk  = blockIdx.x;
    const int tx   = blk & 7;            // W/TW = 8
    const int rest = blk >> 3;
    const int ty   = rest & 31;          // H/TH = 32
    const int b    = rest >> 5;          // B = 16
    const int x0 = tx * TW, y0 = ty * TH;
    const int tid = threadIdx.x;

    const float* __restrict__ xb = x + (size_t)b * CC * HH * WW;

    // Cooperative halo load with circular wrap: 16*10*34 = 5440 elems / 256 thr
    for (int i = tid; i < CC * (TH + 2) * (TW + 2); i += 256) {
        int c  = i / ((TH + 2) * (TW + 2));
        int r  = i % ((TH + 2) * (TW + 2));
        int yy = r / (TW + 2);
        int xx = r % (TW + 2);
        int gy = (y0 + yy - 1 + HH) & (HH - 1);
        int gx = (x0 + xx - 1 + WW) & (WW - 1);
        tile[c][yy][xx] = xb[((size_t)c * HH + gy) * WW + gx];
    }
    __syncthreads();

    const int lx = tid & (TW - 1);
    const int ly = tid / TW;

    // Perception vector in registers: p[0:16]=x, p[16:32]=gx, p[32:48]=gy
    float p[PC];
#pragma unroll
    for (int c = 0; c < CC; ++c) {
        float a00 = tile[c][ly][lx],     a01 = tile[c][ly][lx + 1],     a02 = tile[c][ly][lx + 2];
        float a10 = tile[c][ly + 1][lx],                                a12 = tile[c][ly + 1][lx + 2];
        float a20 = tile[c][ly + 2][lx], a21 = tile[c][ly + 2][lx + 1], a22 = tile[c][ly + 2][lx + 2];
        p[c] = tile[c][ly + 1][lx + 1];
        // Sobel X (cross-correlation, no flip): [[-1,0,1],[-2,0,2],[-1,0,1]]
        p[CC + c] = (a02 - a00) + 2.0f * (a12 - a10) + (a22 - a20);
        // Sobel Y = X^T: [[-1,-2,-1],[0,0,0],[1,2,1]]
        p[2 * CC + c] = (a20 - a00) + 2.0f * (a21 - a01) + (a22 - a02);
    }

    float ds[OUTC];
#pragma unroll
    for (int j = 0; j < OUTC; ++j) ds[j] = 0.0f;

    // MLP: h_o = relu(b1[o] + w1[o,:] . p); ds += h_o * w2[:,o]
    // o, c indices are wave-uniform -> weight reads become s_load (scalar pipe)
    for (int o = 0; o < HID; ++o) {
        const float* __restrict__ wr = w1 + o * PC;
        float a0 = b1[o], a1 = 0.0f, a2 = 0.0f, a3 = 0.0f;
#pragma unroll
        for (int c = 0; c < PC; c += 4) {
            a0 = fmaf(wr[c + 0], p[c + 0], a0);
            a1 = fmaf(wr[c + 1], p[c + 1], a1);
            a2 = fmaf(wr[c + 2], p[c + 2], a2);
            a3 = fmaf(wr[c + 3], p[c + 3], a3);
        }
        float h = (a0 + a1) + (a2 + a3);
        h = fmaxf(h, 0.0f);
#pragma unroll
        for (int j = 0; j < OUTC; ++j) ds[j] = fmaf(w2[j * HID + o], h, ds[j]);
    }

    // Residual write: channels 0..2 passthrough, 3..15 += ds
    const size_t base = (size_t)b * CC * HH * WW + (size_t)(y0 + ly) * WW + (x0 + lx);
#pragma unroll
    for (int c = 0; c < 3; ++c)
        out[base + (size_t)c * HH * WW] = p[c];
#pragma unroll
    for (int c = 3; c < CC; ++c)
        out[base + (size_t)c * HH * WW] = p[c] + ds[c - 3];
}

extern "C" void kernel_launch(void* const* d_in, const int* in_sizes, int n_in,
                              void* d_out, int out_size, void* d_ws, size_t ws_size,
                              hipStream_t stream) {
    const float* x  = (const float*)d_in[0];
    const float* w1 = (const float*)d_in[1];
    const float* b1 = (const float*)d_in[2];
    const float* w2 = (const float*)d_in[3];
    float* out = (float*)d_out;

    // 16 images * 32 y-tiles * 8 x-tiles = 4096 blocks of 256 threads
    dim3 grid(BB * (HH / TH) * (WW / TW));
    dim3 block(256);
    hipLaunchKernelGGL(gca_kernel, grid, block, 0, stream, x, w1, b1, w2, out);
}

// Round 2
// 214.439 us; speedup vs baseline: 1.7207x; 1.7207x over previous
//
#include <hip/hip_runtime.h>

// Problem constants
#define BB   16
#define CC   16
#define HH   256
#define WW   256
#define HID  128
#define OUTC 13

typedef short short8 __attribute__((ext_vector_type(8)));
typedef float floatx16 __attribute__((ext_vector_type(16)));

// ---- helpers ----
__device__ __forceinline__ unsigned short f2bf(float x) {
    unsigned int u = __float_as_uint(x);
    u += 0x7fffu + ((u >> 16) & 1u);          // round-to-nearest-even
    return (unsigned short)(u >> 16);
}

// ws layout: W1F frags [mtG 0..3][tap 0..8][lane 0..63][8 bf16]  = 36864 B
//            W2F frags [s 0..7][lane 0..63][8 bf16]              =  8192 B at +36864
#define W1F_BYTES 36864
#define W2F_OFF   36864

// ================= prep kernel: bake bf16 weight fragments ==================
__global__ __launch_bounds__(256) void gca_prep(
    const float* __restrict__ w1, const float* __restrict__ w2,
    unsigned char* __restrict__ ws)
{
    const int id = blockIdx.x * 256 + threadIdx.x;   // 2816 total
    // Sobel (cross-correlation, row-major over dy,dx)
    const float SX[9] = {-1.f, 0.f, 1.f, -2.f, 0.f, 2.f, -1.f, 0.f, 1.f};
    const float SY[9] = {-1.f, -2.f, -1.f, 0.f, 0.f, 0.f, 1.f, 2.f, 1.f};

    if (id < 2304) {                                  // W1eff frags
        const int mtG  = id / 576;
        const int rem  = id % 576;
        const int tap  = rem / 64;
        const int lane = rem % 64;
        const int p  = lane & 31, hi = lane >> 5;
        const int hid = 32 * mtG + p;
        const float cen = (tap == 4) ? 1.f : 0.f;
        const float sxv = SX[tap], syv = SY[tap];
        const float* wr = w1 + hid * 48;
        unsigned int o[4];
        for (int k = 0; k < 4; ++k) {
            int c0 = 8 * hi + 2 * k;
            float v0 = wr[c0]     * cen + wr[16 + c0]     * sxv + wr[32 + c0]     * syv;
            float v1 = wr[c0 + 1] * cen + wr[16 + c0 + 1] * sxv + wr[32 + c0 + 1] * syv;
            o[k] = (unsigned int)f2bf(v0) | ((unsigned int)f2bf(v1) << 16);
        }
        *(uint4*)(ws + (size_t)id * 16) = make_uint4(o[0], o[1], o[2], o[3]);
    } else if (id < 2816) {                           // W2 (padded outc 13->32) frags
        const int id2 = id - 2304;
        const int s    = id2 / 64;
        const int lane = id2 % 64;
        const int outc = lane & 31, hi = lane >> 5;
        unsigned int o[4];
        for (int k = 0; k < 4; ++k) {
            int hid0 = 16 * s + 8 * hi + 2 * k;
            float v0 = (outc < OUTC) ? w2[outc * HID + hid0]     : 0.f;
            float v1 = (outc < OUTC) ? w2[outc * HID + hid0 + 1] : 0.f;
            o[k] = (unsigned int)f2bf(v0) | ((unsigned int)f2bf(v1) << 16);
        }
        *(uint4*)(ws + W2F_OFF + (size_t)id2 * 16) = make_uint4(o[0], o[1], o[2], o[3]);
    }
}

// ================= main kernel ==============================================
// Block = 256 thr = 4 waves = 2 pairs. Pair P handles pixel-row y0+2t+P each of
// 8 iterations; within a pair, wave hw in {0,1} owns hidden units 64*hw..64*hw+63.
// LDS: bf16 input tile [18 rows][34 cols][16 c] with 40B pixel stride (6120 dw)
//      + pair-combine buffer 2*64*18 dw (padded stride 18 -> 2-way banks).
#define TILE_DW 6120
#define CBUF_DW 2304

__global__ __launch_bounds__(256) void gca_main(
    const float* __restrict__ in,
    const float* __restrict__ b1,
    const unsigned char* __restrict__ ws,
    float* __restrict__ out)
{
    __shared__ unsigned int lds[TILE_DW + CBUF_DW];

    const int tid  = threadIdx.x;
    const int wid  = tid >> 6;
    const int lane = tid & 63;
    const int hw   = wid & 1;      // hid-half
    const int P    = wid >> 1;     // pair id
    const int p    = lane & 31;    // pixel-in-group / m-index
    const int hi   = lane >> 5;    // k-half selector

    const int bI = blockIdx.x >> 7;          // image
    const int rm = blockIdx.x & 127;
    const int y0 = (rm >> 3) << 4;           // 16-row span
    const int x0 = (rm & 7)  << 5;           // 32-px span

    // ---- stage halo tile (rows y0-1..y0+16, cols x0-1..x0+32), fp32 -> bf16 ----
    {
        unsigned short* tus = (unsigned short*)lds;
        const float* inb = in + ((size_t)bI << 20);     // bI*16*65536
        for (int i = tid; i < 16 * 18 * 34; i += 256) {
            int c   = i / 612;
            int rem = i % 612;
            int row = rem / 34;
            int col = rem % 34;
            int y = (y0 + row - 1) & 255;
            int x = (x0 + col - 1) & 255;
            float v = inb[(c << 16) + (y << 8) + x];
            tus[(row * 34 + col) * 20 + c] = f2bf(v);
        }
    }
    __syncthreads();

    const unsigned char* w1f = ws + ((size_t)(2 * hw) * 9) * 64 * 16; // mtG base = 2*hw
    const unsigned char* w2f = ws + W2F_OFF + (size_t)(4 * hw) * 64 * 16;
    const int cb = TILE_DW + P * (64 * 18) + lane * 18;

#pragma unroll 1
    for (int t = 0; t < 8; ++t) {
        const int row = y0 + 2 * t + P;          // image row of this pair

        // ---- acc init = b1 (pre-relu bias) ----
        floatx16 acc1[2];
#pragma unroll
        for (int m = 0; m < 2; ++m) {
            const int hb = 64 * hw + 32 * m + 4 * hi;
#pragma unroll
            for (int rr = 0; rr < 4; ++rr) {
                float4 bv = *(const float4*)(b1 + hb + 8 * rr);
                acc1[m][4 * rr + 0] = bv.x;
                acc1[m][4 * rr + 1] = bv.y;
                acc1[m][4 * rr + 2] = bv.z;
                acc1[m][4 * rr + 3] = bv.w;
            }
        }

        // ---- GEMM1: 9 taps (K=16 each), A = W1eff frags, B = bf16 pixel tile ----
#pragma unroll
        for (int tap = 0; tap < 9; ++tap) {
            const int tr  = 2 * t + P + tap / 3;        // tile row (dy+1 folded in)
            const int col = p + tap % 3;                // tile col (dx+1 folded in)
            const int dwo = (tr * 34 + col) * 10 + 4 * hi;
            union { unsigned int u[4]; short8 s; } bfr;
            uint2 lo2 = *(const uint2*)&lds[dwo];
            uint2 hi2 = *(const uint2*)&lds[dwo + 2];
            bfr.u[0] = lo2.x; bfr.u[1] = lo2.y; bfr.u[2] = hi2.x; bfr.u[3] = hi2.y;
#pragma unroll
            for (int m = 0; m < 2; ++m) {
                short8 af = *(const short8*)(w1f + (size_t)((m * 9 + tap) * 64 + lane) * 16);
                acc1[m] = __builtin_amdgcn_mfma_f32_32x32x16_bf16(af, bfr.s, acc1[m], 0, 0, 0);
            }
        }

        // ---- relu + pack h into 8 runs of 4 bf16 (uint2 each) ----
        uint2 hrun[8];
#pragma unroll
        for (int m = 0; m < 2; ++m)
#pragma unroll
            for (int rr = 0; rr < 4; ++rr) {
                float h0 = fmaxf(acc1[m][4 * rr + 0], 0.f);
                float h1 = fmaxf(acc1[m][4 * rr + 1], 0.f);
                float h2 = fmaxf(acc1[m][4 * rr + 2], 0.f);
                float h3 = fmaxf(acc1[m][4 * rr + 3], 0.f);
                hrun[4 * m + rr].x = (unsigned int)f2bf(h0) | ((unsigned int)f2bf(h1) << 16);
                hrun[4 * m + rr].y = (unsigned int)f2bf(h2) | ((unsigned int)f2bf(h3) << 16);
            }

        // ---- GEMM2 (partial over this wave's 64 hids): D[outc32][pixel32] ----
        floatx16 acc2 = {};
#pragma unroll
        for (int sp = 0; sp < 4; ++sp) {
            uint2 r0 = hrun[2 * sp];
            uint2 r1 = hrun[2 * sp + 1];
            uint2 x0s, x1s;
            x0s.x = (unsigned int)__shfl_xor((int)r0.x, 32);
            x0s.y = (unsigned int)__shfl_xor((int)r0.y, 32);
            x1s.x = (unsigned int)__shfl_xor((int)r1.x, 32);
            x1s.y = (unsigned int)__shfl_xor((int)r1.y, 32);
            union { unsigned int u[4]; short8 s; } b2;
            uint2 lo = hi ? x1s : r0;     // k = 16s+8hi+{0..3} from hi=0 half
            uint2 hg = hi ? r1  : x0s;    // k = 16s+8hi+{4..7} from hi=1 half
            b2.u[0] = lo.x; b2.u[1] = lo.y; b2.u[2] = hg.x; b2.u[3] = hg.y;
            short8 a2 = *(const short8*)(w2f + (size_t)(sp * 64 + lane) * 16);
            acc2 = __builtin_amdgcn_mfma_f32_32x32x16_bf16(a2, b2.s, acc2, 0, 0, 0);
        }

        // ---- pair combine: wave1 -> LDS ----
        if (hw == 1) {
#pragma unroll
            for (int k = 0; k < 8; ++k) {
                uint2 v;
                v.x = __float_as_uint(acc2[2 * k]);
                v.y = __float_as_uint(acc2[2 * k + 1]);
                *(uint2*)&lds[cb + 2 * k] = v;
            }
        }
        __syncthreads();

        if (hw == 0) {
            // full ds = own partial + partner partial; residual add; store ch 3..15
#pragma unroll
            for (int r = 0; r < 16; ++r) {
                int outc = (r & 3) + 8 * (r >> 2) + 4 * hi;
                if (outc < OUTC) {
                    float sum = acc2[r] + __uint_as_float(lds[cb + r]);
                    int idx = ((bI * 16 + 3 + outc) << 16) + (row << 8) + x0 + p;
                    out[idx] = in[idx] + sum;
                }
            }
        } else {
            // passthrough channels 0..2 for this pair's row
#pragma unroll
            for (int k = 0; k < 2; ++k) {
                int e = lane + 64 * k;
                if (e < 96) {
                    int c  = e >> 5;
                    int px = e & 31;
                    int idx = ((bI * 16 + c) << 16) + (row << 8) + x0 + px;
                    out[idx] = in[idx];
                }
            }
        }
        __syncthreads();   // protect cbuf reuse next iteration
    }
}

extern "C" void kernel_launch(void* const* d_in, const int* in_sizes, int n_in,
                              void* d_out, int out_size, void* d_ws, size_t ws_size,
                              hipStream_t stream) {
    const float* x  = (const float*)d_in[0];
    const float* w1 = (const float*)d_in[1];
    const float* b1 = (const float*)d_in[2];
    const float* w2 = (const float*)d_in[3];
    float* out = (float*)d_out;
    unsigned char* ws = (unsigned char*)d_ws;

    hipLaunchKernelGGL(gca_prep, dim3(11), dim3(256), 0, stream, w1, w2, ws);
    hipLaunchKernelGGL(gca_main, dim3(2048), dim3(256), 0, stream, x, b1, ws, out);
}